// Round 3
// baseline (96.060 us; speedup 1.0000x reference)
//
#include <hip/hip_runtime.h>
#include <hip/hip_cooperative_groups.h>
#include <math.h>

namespace cg = cooperative_groups;

// Problem constants (match reference)
constexpr int B = 4, S = 128, D = 256, TC = 1024;  // TC = D*4 (d,c flattened)
constexpr float EPS = 1e-6f;
constexpr int KS = 16, KW = 64;      // split-K for G (KS*KW = TC)
constexpr int ITS = 16, IR = 8;      // i-tiles for G: 16 tiles x 8 rows
constexpr int ROWS = 8, TCOLS = 256; // attn tiling

// ws layout (floats): Wq[S][TC] | Wk[S][TC] | Wv[S][TC] | SWq[S][4] | SWk[S][4]
//                     | Gpart[KS][S][S]

__global__ __launch_bounds__(256)
void qlns_fused(const float* __restrict__ query, const float* __restrict__ key_in,
                const float* __restrict__ value,
                const float* __restrict__ qw, const float* __restrict__ qb,
                const float* __restrict__ kw, const float* __restrict__ kb,
                const float* __restrict__ vw, const float* __restrict__ vb,
                float* __restrict__ Wq, float* __restrict__ Wk, float* __restrict__ Wv,
                float* __restrict__ SWq, float* __restrict__ SWk,
                float* __restrict__ Gpart, float* __restrict__ out)
{
    // LDS union: P2 needs KW*(S+1) + IR*(KW+1) = 8256+520 floats (~35 KB) max
    __shared__ float sh[KW * (S + 1) + IR * (KW + 1)];

    cg::grid_group grid = cg::this_grid();
    const int blk = blockIdx.x, tid = threadIdx.x;

    // ---------------- P1: exp tables + column sums (128 blocks) ----------------
    if (blk < S) {
        float* redq = sh;          // [256]
        float* redk = sh + 256;    // [256]
        const int s = blk;
        float pq = 0.f, pk = 0.f;
        #pragma unroll
        for (int r = 0; r < 4; ++r) {
            int t = r * 256 + tid;
            int c = t & 3, d = t >> 2;
            int wi = (c * S + s) * D + d;            // [4,S,D]
            float a1 = expf(qw[wi]) + expf(qb[t]);   // qb/kb/vb: [D,4] flat == t
            float a2 = expf(kw[wi]) + expf(kb[t]);
            float a3 = expf(vw[wi]) + expf(vb[t]);
            Wq[s * TC + t] = a1; Wk[s * TC + t] = a2; Wv[s * TC + t] = a3;
            pq += a1; pk += a2;
        }
        redq[tid] = pq; redk[tid] = pk;
        __syncthreads();
        if (tid < 4) {
            float sq = 0.f, sk = 0.f;
            for (int u = tid; u < 256; u += 4) { sq += redq[u]; sk += redk[u]; }
            SWq[s * 4 + tid] = sq; SWk[s * 4 + tid] = sk;
        }
    }
    grid.sync();

    // ---------------- P2: Gpart[ks][i][j] = sum_{k slice} Wq[i,k]*Wk[j,k] ------
    {
        float* wkT = sh;                    // [KW][S+1]
        float* wqs = sh + KW * (S + 1);     // [IR][KW+1]
        const int it = blk >> 4, ks = blk & 15;
        const int k0 = ks * KW;
        for (int e = tid; e < S * KW; e += 256) {
            int j = e >> 6, kk = e & 63;
            wkT[kk * (S + 1) + j] = Wk[j * TC + k0 + kk];
        }
        for (int e = tid; e < IR * KW; e += 256) {
            int i = e >> 6, kk = e & 63;
            wqs[i * (KW + 1) + kk] = Wq[(it * IR + i) * TC + k0 + kk];
        }
        __syncthreads();
        const int j = tid & 127, ih = tid >> 7;
        float acc[4] = {0.f, 0.f, 0.f, 0.f};
        for (int k = 0; k < KW; ++k) {
            float kv = wkT[k * (S + 1) + j];
            #pragma unroll
            for (int r = 0; r < 4; ++r)
                acc[r] += wqs[(ih * 4 + r) * (KW + 1) + k] * kv;
        }
        #pragma unroll
        for (int r = 0; r < 4; ++r) {
            int i = it * IR + ih * 4 + r;
            Gpart[(ks * S + i) * S + j] = acc[r];
        }
        __syncthreads();   // all lanes done with sh before P3 reuses it
    }
    grid.sync();

    // ---------------- P3: scores + softmax + PV ---------------------------------
    {
        float (*att)[S]  = (float(*)[S])sh;            // [ROWS][S]
        float (*xkl)[4]  = (float(*)[4])(sh + 1024);   // [S][4]
        float (*xvl)[4]  = (float(*)[4])(sh + 1536);
        float (*swkl)[4] = (float(*)[4])(sh + 2048);
        float (*xql)[4]  = (float(*)[4])(sh + 2560);   // [ROWS][4]
        float (*swql)[4] = (float(*)[4])(sh + 2592);

        const int tt = blk & 3, yt = (blk >> 2) & 15, b = blk >> 6;
        const int i0 = yt * ROWS;

        for (int e = tid; e < S * 4; e += 256) {
            xkl[e >> 2][e & 3]  = fmaxf(key_in[b * S * 4 + e], EPS);
            xvl[e >> 2][e & 3]  = fmaxf(value[b * S * 4 + e], EPS);
            swkl[e >> 2][e & 3] = SWk[e];
        }
        if (tid < ROWS * 4) {
            xql[tid >> 2][tid & 3]  = fmaxf(query[(b * S + i0) * 4 + tid], EPS);
            swql[tid >> 2][tid & 3] = SWq[i0 * 4 + tid];
        }
        __syncthreads();

        for (int e = tid; e < ROWS * S; e += 256) {
            int i = e >> 7, j = e & 127;
            float g = 0.f;
            #pragma unroll
            for (int ks = 0; ks < KS; ++ks) g += Gpart[(ks * S + i0 + i) * S + j];
            float sc = g;
            #pragma unroll
            for (int c = 0; c < 4; ++c)
                sc += (float)D * xql[i][c] * xkl[j][c]
                    + xql[i][c] * swkl[j][c] + swql[i][c] * xkl[j][c];
            att[i][j] = sc;
        }
        __syncthreads();

        {
            const int w = tid >> 6, lane = tid & 63;
            #pragma unroll
            for (int rr = 0; rr < ROWS / 4; ++rr) {
                int i = w + rr * 4;
                float s0 = att[i][lane], s1 = att[i][lane + 64];
                float m = fmaxf(s0, s1);
                #pragma unroll
                for (int o = 32; o > 0; o >>= 1) m = fmaxf(m, __shfl_xor(m, o));
                float e0 = expf(s0 - m), e1 = expf(s1 - m);
                float sum = e0 + e1;
                #pragma unroll
                for (int o = 32; o > 0; o >>= 1) sum += __shfl_xor(sum, o);
                float inv = 1.f / sum;
                att[i][lane]      = fmaxf(e0 * inv, EPS);   // _to_log(attn) clamp
                att[i][lane + 64] = fmaxf(e1 * inv, EPS);
            }
        }
        __syncthreads();

        const int t = tt * TCOLS + tid;
        const int c = t & 3;
        float acc[ROWS];
        #pragma unroll
        for (int i = 0; i < ROWS; ++i) acc[i] = 0.f;
        for (int j = 0; j < S; ++j) {
            float v = Wv[j * TC + t] + xvl[j][c];
            #pragma unroll
            for (int i = 0; i < ROWS; ++i) acc[i] += att[i][j] * v;
        }
        float* ob = out + (size_t)(b * S + i0) * TC + t;
        #pragma unroll
        for (int i = 0; i < ROWS; ++i) ob[i * TC] = acc[i];
    }
}

extern "C" void kernel_launch(void* const* d_in, const int* in_sizes, int n_in,
                              void* d_out, int out_size, void* d_ws, size_t ws_size,
                              hipStream_t stream)
{
    const float* query  = (const float*)d_in[0];
    const float* key_in = (const float*)d_in[1];
    const float* value  = (const float*)d_in[2];
    const float* qw = (const float*)d_in[3];
    const float* qb = (const float*)d_in[4];
    const float* kw = (const float*)d_in[5];
    const float* kb = (const float*)d_in[6];
    const float* vw = (const float*)d_in[7];
    const float* vb = (const float*)d_in[8];
    float* out = (float*)d_out;

    float* Wq    = (float*)d_ws;
    float* Wk    = Wq + (size_t)S * TC;
    float* Wv    = Wk + (size_t)S * TC;
    float* SWq   = Wv + (size_t)S * TC;
    float* SWk   = SWq + S * 4;
    float* Gpart = SWk + S * 4;          // [KS][S][S] = 1 MB

    void* args[] = {
        (void*)&query, (void*)&key_in, (void*)&value,
        (void*)&qw, (void*)&qb, (void*)&kw, (void*)&kb, (void*)&vw, (void*)&vb,
        (void*)&Wq, (void*)&Wk, (void*)&Wv, (void*)&SWq, (void*)&SWk,
        (void*)&Gpart, (void*)&out
    };
    hipLaunchCooperativeKernel((const void*)qlns_fused, dim3(B * S / ROWS * (TC / TCOLS)),
                               dim3(256), args, 0, stream);
}

// Round 4
// 30.735 us; speedup vs baseline: 3.1254x; 3.1254x over previous
//
#include <hip/hip_runtime.h>
#include <math.h>

// Problem constants (match reference)
constexpr int B = 4, S = 128, D = 256, TC = 1024;  // TC = D*4 (d,c flattened)
constexpr float EPS = 1e-6f;
constexpr int KS = 16, KW = 64;      // split-K for G (KS*KW = TC)
constexpr int ROWS = 8, TCOLS = 256; // KB tiling

// ws layout (floats): Wv[S][TC] | SWq[S][4] | SWk[S][4] | Gpart[KS][S][S]

// ---------------------------------------------------------------------------
// KA: 256 independent blocks, two roles.
//  blk <  128: (it = blk>>4, ks = blk&15)
//     Gpart[ks][i][j] = sum_{k in slice} Wq[i,k]*Wk[j,k],
//     with Wq/Wk elements computed inline: W[s,t] = exp(w[c,s,d]) + exp(bias[t]).
//  blk >= 128: s = blk-128
//     Wv[s][t] = exp(vw)+exp(vb);  SWq/SWk[s][c] = sum_d (exp(w)+exp(bias)).
// ---------------------------------------------------------------------------
__global__ __launch_bounds__(256)
void kA(const float* __restrict__ qw, const float* __restrict__ qb,
        const float* __restrict__ kw, const float* __restrict__ kb,
        const float* __restrict__ vw, const float* __restrict__ vb,
        float* __restrict__ Wv, float* __restrict__ SWq, float* __restrict__ SWk,
        float* __restrict__ Gpart)
{
    __shared__ float wkT[KW][S + 1];   // exp'd K slice, transposed
    __shared__ float wqs[16][KW + 1];  // exp'd Q tile
    __shared__ float ekb[KW], eqb[KW];
    __shared__ float redq[256], redk[256];

    const int blk = blockIdx.x, tid = threadIdx.x;

    if (blk < 128) {
        const int it = blk >> 4, ks = blk & 15;
        const int k0 = ks * KW, d0 = k0 >> 2, i0 = it * 16;

        if (tid < KW) {
            int t = k0 + tid;
            ekb[tid] = expf(kb[t]);
            eqb[tid] = expf(qb[t]);
        }
        __syncthreads();

        // K slice: [4c][128j][16dd] -> wkT[kk][j], kk = dd*4+c
        for (int e = tid; e < 4 * S * 16; e += 256) {
            int c = e >> 11, j = (e >> 4) & 127, dd = e & 15;
            int kk = dd * 4 + c;
            wkT[kk][j] = expf(kw[(c * S + j) * D + d0 + dd]) + ekb[kk];
        }
        // Q tile: [4c][16i][16dd] -> wqs[i][kk]
        for (int e = tid; e < 4 * 16 * 16; e += 256) {
            int c = e >> 8, i = (e >> 4) & 15, dd = e & 15;
            int kk = dd * 4 + c;
            wqs[i][kk] = expf(qw[(c * S + i0 + i) * D + d0 + dd]) + eqb[kk];
        }
        __syncthreads();

        const int j = tid & 127, ih = tid >> 7;
        float acc[8] = {0.f,0.f,0.f,0.f,0.f,0.f,0.f,0.f};
        for (int k = 0; k < KW; ++k) {
            float kv = wkT[k][j];
            #pragma unroll
            for (int r = 0; r < 8; ++r) acc[r] += wqs[ih * 8 + r][k] * kv;
        }
        #pragma unroll
        for (int r = 0; r < 8; ++r) {
            int i = i0 + ih * 8 + r;
            Gpart[(ks * S + i) * S + j] = acc[r];
        }
    } else {
        const int s = blk - 128;
        float pq = 0.f, pk = 0.f;
        #pragma unroll
        for (int r = 0; r < 4; ++r) {
            int t = r * 256 + tid;
            int c = t & 3, d = t >> 2;
            int wi = (c * S + s) * D + d;            // [4,S,D]
            pq += expf(qw[wi]) + expf(qb[t]);
            pk += expf(kw[wi]) + expf(kb[t]);
            Wv[s * TC + t] = expf(vw[wi]) + expf(vb[t]);
        }
        redq[tid] = pq; redk[tid] = pk;
        __syncthreads();
        if (tid < 4) {  // c == tid&3 invariant per thread
            float sq = 0.f, sk = 0.f;
            for (int u = tid; u < 256; u += 4) { sq += redq[u]; sk += redk[u]; }
            SWq[s * 4 + tid] = sq; SWk[s * 4 + tid] = sk;
        }
    }
}

// ---------------------------------------------------------------------------
// KB: fused scores (factorized) + softmax + PV for (b, 8 rows, 256 t-cols).
//   scores[i,j] = sum_ks Gpart + sum_c { D*xq*xk + xq*SWk[j] + SWq[i]*xk }
// ---------------------------------------------------------------------------
__global__ __launch_bounds__(256)
void kB(const float* __restrict__ query, const float* __restrict__ key_in,
        const float* __restrict__ value,
        const float* __restrict__ Wv, const float* __restrict__ SWq,
        const float* __restrict__ SWk, const float* __restrict__ Gpart,
        float* __restrict__ out)
{
    __shared__ float att[ROWS][S];
    __shared__ float xkl[S][4], xvl[S][4], swkl[S][4];
    __shared__ float xql[ROWS][4], swql[ROWS][4];
    const int tt = blockIdx.x, i0 = blockIdx.y * ROWS, b = blockIdx.z;
    const int tid = threadIdx.x;

    for (int e = tid; e < S * 4; e += 256) {
        xkl[e >> 2][e & 3]  = fmaxf(key_in[b * S * 4 + e], EPS);
        xvl[e >> 2][e & 3]  = fmaxf(value[b * S * 4 + e], EPS);
        swkl[e >> 2][e & 3] = SWk[e];
    }
    if (tid < ROWS * 4) {
        xql[tid >> 2][tid & 3]  = fmaxf(query[(b * S + i0) * 4 + tid], EPS);
        swql[tid >> 2][tid & 3] = SWq[i0 * 4 + tid];
    }
    __syncthreads();

    for (int e = tid; e < ROWS * S; e += 256) {
        int i = e >> 7, j = e & 127;
        float g = 0.f;
        #pragma unroll
        for (int ks = 0; ks < KS; ++ks) g += Gpart[(ks * S + i0 + i) * S + j];
        float sc = g;
        #pragma unroll
        for (int c = 0; c < 4; ++c)
            sc += (float)D * xql[i][c] * xkl[j][c]
                + xql[i][c] * swkl[j][c] + swql[i][c] * xkl[j][c];
        att[i][j] = sc;
    }
    __syncthreads();

    {
        const int w = tid >> 6, lane = tid & 63;
        #pragma unroll
        for (int rr = 0; rr < ROWS / 4; ++rr) {
            int i = w + rr * 4;
            float s0 = att[i][lane], s1 = att[i][lane + 64];
            float m = fmaxf(s0, s1);
            #pragma unroll
            for (int o = 32; o > 0; o >>= 1) m = fmaxf(m, __shfl_xor(m, o));
            float e0 = expf(s0 - m), e1 = expf(s1 - m);
            float sum = e0 + e1;
            #pragma unroll
            for (int o = 32; o > 0; o >>= 1) sum += __shfl_xor(sum, o);
            float inv = 1.f / sum;
            att[i][lane]      = fmaxf(e0 * inv, EPS);   // _to_log(attn) clamp
            att[i][lane + 64] = fmaxf(e1 * inv, EPS);
        }
    }
    __syncthreads();

    const int t = tt * TCOLS + tid;
    const int c = t & 3;
    float acc[ROWS];
    #pragma unroll
    for (int i = 0; i < ROWS; ++i) acc[i] = 0.f;
    for (int j = 0; j < S; ++j) {
        float v = Wv[j * TC + t] + xvl[j][c];
        #pragma unroll
        for (int i = 0; i < ROWS; ++i) acc[i] += att[i][j] * v;
    }
    float* ob = out + (size_t)(b * S + i0) * TC + t;
    #pragma unroll
    for (int i = 0; i < ROWS; ++i) ob[i * TC] = acc[i];
}

extern "C" void kernel_launch(void* const* d_in, const int* in_sizes, int n_in,
                              void* d_out, int out_size, void* d_ws, size_t ws_size,
                              hipStream_t stream)
{
    const float* query  = (const float*)d_in[0];
    const float* key_in = (const float*)d_in[1];
    const float* value  = (const float*)d_in[2];
    const float* qw = (const float*)d_in[3];
    const float* qb = (const float*)d_in[4];
    const float* kw = (const float*)d_in[5];
    const float* kb = (const float*)d_in[6];
    const float* vw = (const float*)d_in[7];
    const float* vb = (const float*)d_in[8];
    float* out = (float*)d_out;

    float* Wv    = (float*)d_ws;
    float* SWq   = Wv + (size_t)S * TC;
    float* SWk   = SWq + S * 4;
    float* Gpart = SWk + S * 4;          // [KS][S][S] = 1 MB

    kA<<<256, 256, 0, stream>>>(qw, qb, kw, kb, vw, vb, Wv, SWq, SWk, Gpart);
    kB<<<dim3(TC / TCOLS, S / ROWS, B), 256, 0, stream>>>(
        query, key_in, value, Wv, SWq, SWk, Gpart, out);
}

// Round 5
// 28.599 us; speedup vs baseline: 3.3589x; 1.0747x over previous
//
#include <hip/hip_runtime.h>
#include <math.h>

// Problem constants (match reference)
constexpr int B = 4, S = 128, D = 256, TC = 1024;  // TC = D*4 (d,c flattened)
constexpr float EPS = 1e-6f;
constexpr int KS = 16, KW = 64;      // split-K for G (KS*KW = TC)
constexpr int ROWS = 8, TCOLS = 256; // KB tiling
constexpr int JH = 64;               // j-half for KB's LDS-staged PV

// ws layout (floats): Wv[S][TC] | SWq[S][4] | SWk[S][4] | Gpart[KS][S][S]

// ---------------------------------------------------------------------------
// KA: 256 independent blocks, two roles.
//  blk <  128: (it = blk>>4, ks = blk&15)
//     Gpart[ks][i][j] = sum_{k in slice} Wq[i,k]*Wk[j,k],
//     Wq/Wk computed inline: W[s,t] = __expf(w[c,s,d]) + __expf(bias[t]).
//  blk >= 128: s = blk-128
//     Wv[s][t] = exp(vw)+exp(vb);  SWq/SWk[s][c] = sum_d (exp(w)+exp(bias)).
// ---------------------------------------------------------------------------
__global__ __launch_bounds__(256)
void kA(const float* __restrict__ qw, const float* __restrict__ qb,
        const float* __restrict__ kw, const float* __restrict__ kb,
        const float* __restrict__ vw, const float* __restrict__ vb,
        float* __restrict__ Wv, float* __restrict__ SWq, float* __restrict__ SWk,
        float* __restrict__ Gpart)
{
    __shared__ __align__(16) float wkT[KW][S + 1];   // exp'd K slice, transposed
    __shared__ __align__(16) float wqs[16][KW + 4];  // exp'd Q tile (stride 68: 16B-aligned rows)
    __shared__ float ekb[KW], eqb[KW];
    __shared__ float redq[256], redk[256];

    const int blk = blockIdx.x, tid = threadIdx.x;

    if (blk < 128) {
        const int it = blk >> 4, ks = blk & 15;
        const int k0 = ks * KW, d0 = k0 >> 2, i0 = it * 16;

        if (tid < KW) {
            int t = k0 + tid;
            ekb[tid] = __expf(kb[t]);
            eqb[tid] = __expf(qb[t]);
        }
        __syncthreads();

        // K slice: [4c][128j][16dd] -> wkT[kk][j], kk = dd*4+c  (64B-coalesced reads)
        for (int e = tid; e < 4 * S * 16; e += 256) {
            int c = e >> 11, j = (e >> 4) & 127, dd = e & 15;
            int kk = dd * 4 + c;
            wkT[kk][j] = __expf(kw[(c * S + j) * D + d0 + dd]) + ekb[kk];
        }
        // Q tile: [4c][16i][16dd] -> wqs[i][kk]
        for (int e = tid; e < 4 * 16 * 16; e += 256) {
            int c = e >> 8, i = (e >> 4) & 15, dd = e & 15;
            int kk = dd * 4 + c;
            wqs[i][kk] = __expf(qw[(c * S + i0 + i) * D + d0 + dd]) + eqb[kk];
        }
        __syncthreads();

        const int j = tid & 127, ih = tid >> 7;
        float acc[8] = {0.f,0.f,0.f,0.f,0.f,0.f,0.f,0.f};
        for (int k = 0; k < KW; k += 4) {
            float kv0 = wkT[k][j], kv1 = wkT[k + 1][j];
            float kv2 = wkT[k + 2][j], kv3 = wkT[k + 3][j];
            #pragma unroll
            for (int r = 0; r < 8; ++r) {
                float4 q = *(const float4*)&wqs[ih * 8 + r][k];   // ds_read_b128 broadcast
                acc[r] += q.x * kv0 + q.y * kv1 + q.z * kv2 + q.w * kv3;
            }
        }
        #pragma unroll
        for (int r = 0; r < 8; ++r) {
            int i = i0 + ih * 8 + r;
            Gpart[(ks * S + i) * S + j] = acc[r];
        }
    } else {
        const int s = blk - 128;
        float pq = 0.f, pk = 0.f;
        #pragma unroll
        for (int r = 0; r < 4; ++r) {
            int t = r * 256 + tid;
            int c = t & 3, d = t >> 2;
            int wi = (c * S + s) * D + d;            // [4,S,D]
            pq += __expf(qw[wi]) + __expf(qb[t]);
            pk += __expf(kw[wi]) + __expf(kb[t]);
            Wv[s * TC + t] = __expf(vw[wi]) + __expf(vb[t]);
        }
        redq[tid] = pq; redk[tid] = pk;
        __syncthreads();
        if (tid < 4) {  // c == tid&3 invariant per thread
            float sq = 0.f, sk = 0.f;
            for (int u = tid; u < 256; u += 4) { sq += redq[u]; sk += redk[u]; }
            SWq[s * 4 + tid] = sq; SWk[s * 4 + tid] = sk;
        }
    }
}

// ---------------------------------------------------------------------------
// KB: fused scores (factorized) + softmax + PV for (b, 8 rows, 256 t-cols).
//   scores[i,j] = sum_ks Gpart + sum_c { D*xq*xk + xq*SWk[j] + SWq[i]*xk }
//   PV reads an LDS-staged (Wv + xv) slice, two 64-row halves.
// ---------------------------------------------------------------------------
__global__ __launch_bounds__(256)
void kB(const float* __restrict__ query, const float* __restrict__ key_in,
        const float* __restrict__ value,
        const float* __restrict__ Wv, const float* __restrict__ SWq,
        const float* __restrict__ SWk, const float* __restrict__ Gpart,
        float* __restrict__ out)
{
    __shared__ __align__(16) float att[ROWS][S];        // 4 KB
    __shared__ __align__(16) float wvS[JH][TCOLS];      // 64 KB staged V half
    __shared__ __align__(16) float xkl[S][4], xvl[S][4], swkl[S][4];
    __shared__ float xql[ROWS][4], swql[ROWS][4];
    const int tt = blockIdx.x, i0 = blockIdx.y * ROWS, b = blockIdx.z;
    const int tid = threadIdx.x;

    for (int e = tid; e < S * 4; e += 256) {
        xkl[e >> 2][e & 3]  = fmaxf(key_in[b * S * 4 + e], EPS);
        xvl[e >> 2][e & 3]  = fmaxf(value[b * S * 4 + e], EPS);
        swkl[e >> 2][e & 3] = SWk[e];
    }
    if (tid < ROWS * 4) {
        xql[tid >> 2][tid & 3]  = fmaxf(query[(b * S + i0) * 4 + tid], EPS);
        swql[tid >> 2][tid & 3] = SWq[i0 * 4 + tid];
    }
    __syncthreads();

    // scores
    for (int e = tid; e < ROWS * S; e += 256) {
        int i = e >> 7, j = e & 127;
        float g = 0.f;
        #pragma unroll
        for (int ks = 0; ks < KS; ++ks) g += Gpart[(ks * S + i0 + i) * S + j];
        float sc = g;
        #pragma unroll
        for (int c = 0; c < 4; ++c)
            sc += (float)D * xql[i][c] * xkl[j][c]
                + xql[i][c] * swkl[j][c] + swql[i][c] * xkl[j][c];
        att[i][j] = sc;
    }
    __syncthreads();

    // softmax over j per row; wave w handles rows w and w+4
    {
        const int w = tid >> 6, lane = tid & 63;
        #pragma unroll
        for (int rr = 0; rr < ROWS / 4; ++rr) {
            int i = w + rr * 4;
            float s0 = att[i][lane], s1 = att[i][lane + 64];
            float m = fmaxf(s0, s1);
            #pragma unroll
            for (int o = 32; o > 0; o >>= 1) m = fmaxf(m, __shfl_xor(m, o));
            float e0 = __expf(s0 - m), e1 = __expf(s1 - m);
            float sum = e0 + e1;
            #pragma unroll
            for (int o = 32; o > 0; o >>= 1) sum += __shfl_xor(sum, o);
            float inv = 1.f / sum;
            att[i][lane]      = fmaxf(e0 * inv, EPS);   // _to_log(attn) clamp
            att[i][lane + 64] = fmaxf(e1 * inv, EPS);
        }
    }
    __syncthreads();

    // PV: out[b,i,t] = sum_j att[i][j] * (Wv[j,t] + xv[j,c]), LDS-staged halves
    float acc[ROWS];
    #pragma unroll
    for (int i = 0; i < ROWS; ++i) acc[i] = 0.f;

    for (int h = 0; h < 2; ++h) {
        // stage wvS[jr][col] = Wv[(h*64+jr)][tt*256+col] + xvl[h*64+jr][col&3]
        for (int e = tid; e < JH * 64; e += 256) {          // 16 float4 per thread
            int jr = e >> 6, c4 = (e & 63) * 4;
            float4 wv = *(const float4*)&Wv[(size_t)(h * JH + jr) * TC + tt * TCOLS + c4];
            float4 xv = *(const float4*)&xvl[h * JH + jr][0];  // broadcast
            float4 o;
            o.x = wv.x + xv.x; o.y = wv.y + xv.y;
            o.z = wv.z + xv.z; o.w = wv.w + xv.w;
            *(float4*)&wvS[jr][c4] = o;
        }
        __syncthreads();
        for (int jj = 0; jj < JH; jj += 4) {
            float v0 = wvS[jj][tid],     v1 = wvS[jj + 1][tid];
            float v2 = wvS[jj + 2][tid], v3 = wvS[jj + 3][tid];
            int j = h * JH + jj;
            #pragma unroll
            for (int i = 0; i < ROWS; ++i) {
                float4 a = *(const float4*)&att[i][j];       // broadcast b128
                acc[i] += a.x * v0 + a.y * v1 + a.z * v2 + a.w * v3;
            }
        }
        __syncthreads();   // before next half overwrites wvS
    }

    float* ob = out + (size_t)(b * S + i0) * TC + tt * TCOLS + tid;
    #pragma unroll
    for (int i = 0; i < ROWS; ++i) ob[i * TC] = acc[i];
}

extern "C" void kernel_launch(void* const* d_in, const int* in_sizes, int n_in,
                              void* d_out, int out_size, void* d_ws, size_t ws_size,
                              hipStream_t stream)
{
    const float* query  = (const float*)d_in[0];
    const float* key_in = (const float*)d_in[1];
    const float* value  = (const float*)d_in[2];
    const float* qw = (const float*)d_in[3];
    const float* qb = (const float*)d_in[4];
    const float* kw = (const float*)d_in[5];
    const float* kb = (const float*)d_in[6];
    const float* vw = (const float*)d_in[7];
    const float* vb = (const float*)d_in[8];
    float* out = (float*)d_out;

    float* Wv    = (float*)d_ws;
    float* SWq   = Wv + (size_t)S * TC;
    float* SWk   = SWq + S * 4;
    float* Gpart = SWk + S * 4;          // [KS][S][S] = 1 MB

    kA<<<256, 256, 0, stream>>>(qw, qb, kw, kb, vw, vb, Wv, SWq, SWk, Gpart);
    kB<<<dim3(TC / TCOLS, S / ROWS, B), 256, 0, stream>>>(
        query, key_in, value, Wv, SWq, SWk, Gpart, out);
}